// Round 1
// 191.952 us; speedup vs baseline: 1.0428x; 1.0428x over previous
//
#include <hip/hip_runtime.h>
#include <hip/hip_bf16.h>
#include <stdint.h>

// B=2, L=2048, E=1024, H=16, Dh=64. f32 in/out; bf16 MFMA compute.
// Layouts (workspace, produced by proj_gemm):
//   QH [b,h,q,64d]               : q-row = 128B contiguous
//   KH [b,h,kt][dh2][64k][32d]   : 8KB/tile, XOR-swizzled: byte ^= ((key>>1)&3)<<4
//   VTB[b,h,kt][kk2][64d][32k]   : 8KB/tile, XOR-swizzled: byte ^= ((d>>1)&3)<<4
// The swizzle makes attn's ds_read_b128 fragment reads bank-conflict-free
// (2 lanes/bank-slot per 16-lane phase) while keeping global_load_lds staging
// a verbatim linear copy (rule: swizzle source+read, never the LDS dest).
#define B_    2
#define SEQ   2048
#define EMB   1024
#define BIGF  1e10f
#define LOG2E 1.4426950408889634f
#define BIG2F (1e10f * LOG2E)
#define C2    (0.125f * LOG2E)

typedef unsigned short u16;
typedef __attribute__((ext_vector_type(4))) u16      u16x4;
typedef __attribute__((ext_vector_type(8))) short    bf8;   // MFMA A/B frag (16B)
typedef __attribute__((ext_vector_type(4))) float    f4;    // MFMA C/D frag
typedef __attribute__((ext_vector_type(4))) float    fv4;

__device__ inline float bf2f(u16 u){ union{uint32_t i; float f;} v; v.i = ((uint32_t)u) << 16; return v.f; }
__device__ inline u16 f2bf(float f){ union{float f; uint32_t i;} v; v.f = f;
                                     uint32_t r = v.i + 0x7fffu + ((v.i >> 16) & 1u); return (u16)(r >> 16); }
__device__ inline float exp2_hw(float x){ float r; asm("v_exp_f32 %0, %1" : "=v"(r) : "v"(x)); return r; }

__device__ inline void gl_lds16(const void* g, void* l){
  __builtin_amdgcn_global_load_lds((const __attribute__((address_space(1))) uint32_t*)g,
                                   (__attribute__((address_space(3))) uint32_t*)l, 16, 0, 0);
}

// ---------------- f32 -> bf16 conversion (6 segments)
struct CvtArgs { const float* src[6]; u16* dst[6]; int n[6]; };

__global__ __launch_bounds__(256) void cvt_bf16(CvtArgs a)
{
  const int seg = blockIdx.y;
  const float* __restrict__ s = a.src[seg];
  u16* __restrict__ d = a.dst[seg];
  const int n = a.n[seg];
  const int i = (blockIdx.x * 256 + threadIdx.x) * 8;
  if (i >= n) return;
  fv4 x0 = *(const fv4*)(s + i);
  fv4 x1 = *(const fv4*)(s + i + 4);
  union { bf8 v; u16 u[8]; } o;
#pragma unroll
  for (int j = 0; j < 4; j++) { o.u[j] = f2bf(x0[j]); o.u[4 + j] = f2bf(x1[j]); }
  *(bf8*)(d + i) = o.v;
}

// ---------------- Projection GEMM (NT), BK=64 (16 iters x 32 MFMA), coalesced epilogues.
__global__ __launch_bounds__(256) void proj_gemm(
    const u16* __restrict__ Xq, const u16* __restrict__ Xk, const u16* __restrict__ Xv,
    const u16* __restrict__ Wq, const u16* __restrict__ Wk, const u16* __restrict__ Wv,
    u16* __restrict__ QH, u16* __restrict__ KH, u16* __restrict__ VTB)
{
  __shared__ u16 smem[18432];       // loop: lA(16KB)+lB(16KB); epilogue: 4 x 64x72 (36KB)
  u16* lA = smem;                   // [kk][128][32]
  u16* lB = smem + 8192;

  const int z = blockIdx.z;
  const u16* X = (z == 0) ? Xq : ((z == 1) ? Xk : Xv);
  const u16* W = (z == 0) ? Wq : ((z == 1) ? Wk : Wv);

  const int tid  = threadIdx.x;
  const int lane = tid & 63;
  const int w    = tid >> 6;
  const int wm   = w >> 1, wn = w & 1;
  const int m0   = blockIdx.x * 128;
  const int n0   = blockIdx.y * 128;
  const int col  = lane & 15, quad = lane >> 4;

  const f4 zero = {0.f, 0.f, 0.f, 0.f};
  f4 acc[4][4];
#pragma unroll
  for (int i = 0; i < 4; i++)
#pragma unroll
    for (int j = 0; j < 4; j++) acc[i][j] = zero;

  for (int k0 = 0; k0 < 1024; k0 += 64) {
    __syncthreads();
#pragma unroll
    for (int j = 0; j < 4; j++) {
      const int kk  = j >> 1;
      const int row = (j & 1) * 64 + w * 16 + (lane >> 2);
      const int cc  = (lane & 3) * 8;
      const size_t g = (size_t)row * 1024 + k0 + kk * 32 + cc;
      gl_lds16(X + (size_t)m0 * 1024 + g, &lA[(j * 256 + w * 64) * 8]);
      gl_lds16(W + (size_t)n0 * 1024 + g, &lB[(j * 256 + w * 64) * 8]);
    }
    __syncthreads();
#pragma unroll
    for (int kk = 0; kk < 2; kk++) {
      const int koff = kk * 4096 + quad * 8;
      bf8 a[4], b[4];
#pragma unroll
      for (int t = 0; t < 4; t++) a[t] = *(const bf8*)&lA[koff + (wm * 64 + t * 16 + col) * 32];
#pragma unroll
      for (int t = 0; t < 4; t++) b[t] = *(const bf8*)&lB[koff + (wn * 64 + t * 16 + col) * 32];
#pragma unroll
      for (int mt = 0; mt < 4; mt++)
#pragma unroll
        for (int nt = 0; nt < 4; nt++)
          acc[mt][nt] = __builtin_amdgcn_mfma_f32_16x16x32_bf16(a[mt], b[nt], acc[mt][nt], 0, 0, 0);
    }
  }

  __syncthreads();
  u16* ep = &smem[w * 4608];            // 64 x 72

  if (z == 2) {
#pragma unroll
    for (int mt = 0; mt < 4; mt++)
#pragma unroll
      for (int nt = 0; nt < 4; nt++) {
        u16x4 pk = { f2bf(acc[mt][nt][0]), f2bf(acc[mt][nt][1]),
                     f2bf(acc[mt][nt][2]), f2bf(acc[mt][nt][3]) };
        *(u16x4*)&ep[(nt * 16 + col) * 72 + mt * 16 + quad * 4] = pk;
      }
  } else {
#pragma unroll
    for (int mt = 0; mt < 4; mt++)
#pragma unroll
      for (int nt = 0; nt < 4; nt++)
#pragma unroll
        for (int r = 0; r < 4; r++)
          ep[(mt * 16 + quad * 4 + r) * 72 + nt * 16 + col] = f2bf(acc[mt][nt][r]);
  }

  const int bb = m0 >> 11;
  const int h  = (n0 >> 6) + wn;
  const int bh = bb * 16 + h;

  if (z == 0) {
    const int qbase = (m0 & 2047) + wm * 64;
    u16* dst = QH + ((size_t)bh * SEQ + qbase) * 64;
#pragma unroll
    for (int i = 0; i < 8; i++) {
      const int f  = i * 1024 + lane * 16;
      const int ml = i * 8 + (lane >> 3), nl = (lane & 7) * 8;
      *(bf8*)(dst + (f >> 1)) = *(const bf8*)&ep[ml * 72 + nl];
    }
  } else if (z == 1) {
    const int kt = (((m0 & 2047) >> 6) + wm);
    u16* dst = KH + (((size_t)bh * 32 + kt) << 12);
#pragma unroll
    for (int i = 0; i < 8; i++) {
      const int f   = i * 1024 + lane * 16;
      const int dh  = f >> 12;
      const int klc = (f >> 6) & 63;
      const int dlo = (lane & 3) * 8;
      const int fs  = f ^ (((klc >> 1) & 3) << 4);   // bank swizzle (within 64B row)
      *(bf8*)(dst + (fs >> 1)) = *(const bf8*)&ep[klc * 72 + dh * 32 + dlo];
    }
  } else {
    const int kt = (((m0 & 2047) >> 6) + wm);
    u16* dst = VTB + (((size_t)bh * 32 + kt) << 12);
#pragma unroll
    for (int i = 0; i < 8; i++) {
      const int f   = i * 1024 + lane * 16;
      const int kk  = f >> 12;
      const int d   = (f >> 6) & 63;
      const int klo = (lane & 3) * 8;
      const int fs  = f ^ (((d >> 1) & 3) << 4);     // bank swizzle (within 64B row)
      *(bf8*)(dst + (fs >> 1)) = *(const bf8*)&ep[d * 72 + kk * 32 + klo];
    }
  }
}

// ---------------- masked V mean (dead-row fallback). One wave per (b, e=h*64+d).
__global__ __launch_bounds__(256) void sumv(const u16* __restrict__ VTB,
                                            const float* __restrict__ vmask,
                                            float* __restrict__ fb)
{
  const int w = threadIdx.x >> 6, lane = threadIdx.x & 63;
  const int gw = blockIdx.x * 4 + w;
  const int b = gw >> 10, e = gw & 1023;
  const int h = e >> 6, d = e & 63;
  const int bh = b * 16 + h;
  const float* vm = vmask + b * SEQ;
  const int ksw = (lane & 31) ^ (((d >> 1) & 3) << 3);   // undo VTB swizzle
  float s = 0.f, c = 0.f;
  for (int kt = 0; kt < 32; kt++) {
    const u16 val = VTB[(((size_t)bh * 32 + kt) << 12) + (lane >> 5) * 2048 + d * 32 + ksw];
    const float m = vm[kt * 64 + lane];
    s += m * bf2f(val); c += m;
  }
#pragma unroll
  for (int o = 1; o < 64; o <<= 1) { s += __shfl_xor(s, o); c += __shfl_xor(c, o); }
  if (lane == 0) fb[gw] = s / c;
}

// ---------------- Flash attention, TRANSPOSED form: S^T = K Q^T, O^T = V^T P^T.
// One block per (b,h,qx): grid 1024 (3 resident blocks/CU vs 2 before).
// Heavy-first qx ordering; XCD-clustered (b,h); double-buffered K/V staging;
// swizzled K/V fragment reads (conflict-free); setprio around MFMA clusters.
__global__ __launch_bounds__(256) void attn(
    const u16* __restrict__ QH, const u16* __restrict__ KH, const u16* __restrict__ VTB,
    const float* __restrict__ vmask, const float* __restrict__ qmask,
    const float* __restrict__ fb, float* __restrict__ OUT)
{
  __shared__ float pen[SEQ];            // (1-vm)*1e10*log2e
  __shared__ u16   sK[2][4096];         // [dh2][64key][32d] x2 (swizzled)
  __shared__ u16   sV[2][4096];         // [kk2][64d][32k]   x2 (swizzled)
  __shared__ u16   P[4 * 16 * 72];      // per-wave P^T as [q16][keypad72]

  const int tid = threadIdx.x, lane = tid & 63, w = tid >> 6;
  const int i   = blockIdx.x;           // 0..1023
  const int xcd = i & 7;
  const int j   = i >> 3;               // 0..127
  const int qx  = j >> 2;               // heavy blocks (small qx) dispatch first
  const int bh  = xcd + 8 * (j & 3);    // 4 (b,h) per XCD for K/V L2 locality
  const int b = bh >> 4, h = bh & 15;
  const int col = lane & 15, quad = lane >> 4;
  const int sq8 = (quad ^ ((col >> 1) & 3)) * 8;   // swizzled k-slot for A-frag reads
  const int wb = w * 16 * 72;

  for (int t = tid; t < SEQ; t += 256)
    pen[t] = (1.0f - vmask[b * SEQ + t]) * BIG2F;

  const u16* kbase = KH  + (((size_t)bh * 32) << 12);
  const u16* vbase = VTB + (((size_t)bh * 32) << 12);

  const int q0 = qx * 64;

  // Q as B-frag: n = q = w*16+col, k = d
  bf8 bQ[2];
#pragma unroll
  for (int dh = 0; dh < 2; dh++)
    bQ[dh] = *(const bf8*)&QH[((size_t)bh * SEQ + q0 + w * 16 + col) * 64 + dh * 32 + quad * 8];

  const f4 zero = {0.f, 0.f, 0.f, 0.f};
  f4 accO[4];                           // O^T: [d-tile nt][r]: d = nt*16+quad*4+r, q = w*16+col
  float l_acc = 0.f;                    // softmax denom for q = w*16+col
#pragma unroll
  for (int t = 0; t < 4; t++) accO[t] = zero;

  {                                     // prologue stage -> buf 0
    const size_t toff = ((size_t)qx << 12) + w * 1024 + lane * 8;
    gl_lds16(kbase + toff,       &sK[0][w * 1024]);
    gl_lds16(kbase + toff + 512, &sK[0][w * 1024 + 512]);
    gl_lds16(vbase + toff,       &sV[0][w * 1024]);
    gl_lds16(vbase + toff + 512, &sV[0][w * 1024 + 512]);
  }

  const int ntile = 32 - qx;
  for (int it = 0; it < ntile; it++) {
    __syncthreads();                    // buf[it&1] staged (+ pen ready at it=0)
    if (it + 1 < ntile) {
      const int nb = (it + 1) & 1;
      const size_t toff = ((size_t)(qx + it + 1) << 12) + w * 1024 + lane * 8;
      gl_lds16(kbase + toff,       &sK[nb][w * 1024]);
      gl_lds16(kbase + toff + 512, &sK[nb][w * 1024 + 512]);
      gl_lds16(vbase + toff,       &sV[nb][w * 1024]);
      gl_lds16(vbase + toff + 512, &sV[nb][w * 1024 + 512]);
    }
    const u16* cK = sK[it & 1];
    const u16* cV = sV[it & 1];
    const int k0 = (qx + it) * 64;

    // S^T = K Q^T : A = K (m=key), B = Q (n=q)
    f4 accS[4];
#pragma unroll
    for (int t = 0; t < 4; t++) accS[t] = zero;
    __builtin_amdgcn_s_setprio(1);
#pragma unroll
    for (int nt = 0; nt < 4; nt++)
#pragma unroll
      for (int dh = 0; dh < 2; dh++) {
        bf8 aK = *(const bf8*)&cK[dh * 2048 + (nt * 16 + col) * 32 + sq8];
        accS[nt] = __builtin_amdgcn_mfma_f32_16x16x32_bf16(aK, bQ[dh], accS[nt], 0, 0, 0);
      }
    __builtin_amdgcn_s_setprio(0);

    // p = exp2(s*C2 - pen2 [- causal]) ; accS[nt][r] = S[key=k0+nt*16+quad*4+r][q]
    float p[4][4];
    fv4 pv[4];
#pragma unroll
    for (int nt = 0; nt < 4; nt++) pv[nt] = *(const fv4*)&pen[k0 + nt * 16 + quad * 4];
    if (it == 0) {                      // diagonal tile: key_local <= q_local penalized
#pragma unroll
      for (int nt = 0; nt < 4; nt++)
#pragma unroll
        for (int r = 0; r < 4; r++) {
          float sv = fmaf(accS[nt][r], C2, -pv[nt][r]);
          if (nt * 16 + quad * 4 + r <= w * 16 + col) sv -= BIG2F;
          p[nt][r] = exp2_hw(sv);
        }
    } else {
#pragma unroll
      for (int nt = 0; nt < 4; nt++)
#pragma unroll
        for (int r = 0; r < 4; r++)
          p[nt][r] = exp2_hw(fmaf(accS[nt][r], C2, -pv[nt][r]));
    }
#pragma unroll
    for (int nt = 0; nt < 4; nt++)
      l_acc += (p[nt][0] + p[nt][1]) + (p[nt][2] + p[nt][3]);

    // P^T -> wave-private LDS [q=col][4 consecutive keys] : one b64 per nt
#pragma unroll
    for (int nt = 0; nt < 4; nt++) {
      union { u16x4 v; u16 u[4]; } pk;
      union { __hip_bfloat162 h2; u16 u[2]; } c0, c1;
      float2 f01; f01.x = p[nt][0]; f01.y = p[nt][1];
      float2 f23; f23.x = p[nt][2]; f23.y = p[nt][3];
      c0.h2 = __float22bfloat162_rn(f01);
      c1.h2 = __float22bfloat162_rn(f23);
      pk.u[0] = c0.u[0]; pk.u[1] = c0.u[1]; pk.u[2] = c1.u[0]; pk.u[3] = c1.u[1];
      *(u16x4*)&P[wb + col * 72 + nt * 16 + quad * 4] = pk.v;
    }

    // O^T += V^T P^T : A = V^T (m=d), B = P^T (n=q, k=key)
    __builtin_amdgcn_s_setprio(1);
#pragma unroll
    for (int kk = 0; kk < 2; kk++) {
      bf8 bP = *(const bf8*)&P[wb + col * 72 + kk * 32 + quad * 8];
#pragma unroll
      for (int nt = 0; nt < 4; nt++) {
        bf8 aV = *(const bf8*)&cV[kk * 2048 + (nt * 16 + col) * 32 + sq8];
        accO[nt] = __builtin_amdgcn_mfma_f32_16x16x32_bf16(aV, bP, accO[nt], 0, 0, 0);
      }
    }
    __builtin_amdgcn_s_setprio(0);
  }

  // epilogue: reduce l over quads (lane bits 4-5), divide, q_mask, dwordx4 stores
  float l = l_acc;
  l += __shfl_xor(l, 16); l += __shfl_xor(l, 32);
  const int q = q0 + w * 16 + col;
  const float qm = qmask[b * SEQ + q];
  float* op = OUT + (size_t)(b * SEQ + q) * EMB + h * 64;
  if (l == 0.0f) {                      // dead row: uniform masked-average fallback
#pragma unroll
    for (int nt = 0; nt < 4; nt++) {
      fv4 f = *(const fv4*)&fb[b * 1024 + h * 64 + nt * 16 + quad * 4];
      f *= qm;
      *(fv4*)(op + nt * 16 + quad * 4) = f;
    }
  } else {
    const float s = qm / l;
#pragma unroll
    for (int nt = 0; nt < 4; nt++) {
      fv4 f = { accO[nt][0] * s, accO[nt][1] * s, accO[nt][2] * s, accO[nt][3] * s };
      *(fv4*)(op + nt * 16 + quad * 4) = f;
    }
  }
}

extern "C" void kernel_launch(void* const* d_in, const int* in_sizes, int n_in,
                              void* d_out, int out_size, void* d_ws, size_t ws_size,
                              hipStream_t stream)
{
  const float* q  = (const float*)d_in[0];
  const float* k  = (const float*)d_in[1];
  const float* v  = (const float*)d_in[2];
  const float* vm = (const float*)d_in[3];
  const float* qm = (const float*)d_in[4];
  const float* Wq = (const float*)d_in[5];
  const float* Wk = (const float*)d_in[6];
  const float* Wv = (const float*)d_in[7];
  float* out = (float*)d_out;

  const size_t NBIG = (size_t)B_ * SEQ * EMB;   // 4 Mi
  const size_t NW   = (size_t)EMB * EMB;        // 1 Mi

  u16* qb  = (u16*)d_ws;
  u16* kb  = qb  + NBIG;
  u16* vb  = kb  + NBIG;
  u16* Wqb = vb  + NBIG;
  u16* Wkb = Wqb + NW;
  u16* Wvb = Wkb + NW;
  u16* QH  = Wvb + NW;
  u16* KH  = QH  + NBIG;
  u16* VTB = KH  + NBIG;
  float* fb = (float*)(VTB + NBIG);             // [2][1024] f32

  CvtArgs ca;
  ca.src[0] = q;  ca.dst[0] = qb;  ca.n[0] = (int)NBIG;
  ca.src[1] = k;  ca.dst[1] = kb;  ca.n[1] = (int)NBIG;
  ca.src[2] = v;  ca.dst[2] = vb;  ca.n[2] = (int)NBIG;
  ca.src[3] = Wq; ca.dst[3] = Wqb; ca.n[3] = (int)NW;
  ca.src[4] = Wk; ca.dst[4] = Wkb; ca.n[4] = (int)NW;
  ca.src[5] = Wv; ca.dst[5] = Wvb; ca.n[5] = (int)NW;

  cvt_bf16<<<dim3((unsigned)(NBIG / 8 / 256), 6, 1), 256, 0, stream>>>(ca);
  proj_gemm<<<dim3(32, 8, 3), 256, 0, stream>>>(qb, kb, vb, Wqb, Wkb, Wvb, QH, KH, VTB);
  sumv<<<dim3(512, 1, 1), 256, 0, stream>>>(VTB, vm, fb);
  attn<<<dim3(1024, 1, 1), 256, 0, stream>>>(QH, KH, VTB, vm, qm, fb, out);
}

// Round 2
// 187.665 us; speedup vs baseline: 1.0666x; 1.0228x over previous
//
#include <hip/hip_runtime.h>
#include <hip/hip_bf16.h>
#include <stdint.h>

// B=2, L=2048, E=1024, H=16, Dh=64. f32 in/out; bf16 MFMA compute.
// Layouts (workspace, produced by proj_gemm):
//   QH [b,h,q,64d]               : q-row = 128B contiguous
//   KH [b,h,kt][dh2][64k][32d]   : 8KB/tile, XOR-swizzled: byte ^= ((key>>1)&3)<<4
//   VTB[b,h,kt][kk2][64d][32k]   : 8KB/tile, XOR-swizzled: byte ^= ((d>>1)&3)<<4
// All LDS tiles staged via global_load_lds are swizzled on the GLOBAL source +
// the ds_read side, never the LDS dest (global_load_lds dest must stay linear).
#define B_    2
#define SEQ   2048
#define EMB   1024
#define BIGF  1e10f
#define LOG2E 1.4426950408889634f
#define BIG2F (1e10f * LOG2E)
#define C2    (0.125f * LOG2E)

typedef unsigned short u16;
typedef __attribute__((ext_vector_type(4))) u16      u16x4;
typedef __attribute__((ext_vector_type(8))) short    bf8;   // MFMA A/B frag (16B)
typedef __attribute__((ext_vector_type(4))) float    f4;    // MFMA C/D frag
typedef __attribute__((ext_vector_type(4))) float    fv4;

__device__ inline float bf2f(u16 u){ union{uint32_t i; float f;} v; v.i = ((uint32_t)u) << 16; return v.f; }
__device__ inline u16 f2bf(float f){ union{float f; uint32_t i;} v; v.f = f;
                                     uint32_t r = v.i + 0x7fffu + ((v.i >> 16) & 1u); return (u16)(r >> 16); }
__device__ inline float exp2_hw(float x){ float r; asm("v_exp_f32 %0, %1" : "=v"(r) : "v"(x)); return r; }

__device__ inline void gl_lds16(const void* g, void* l){
  __builtin_amdgcn_global_load_lds((const __attribute__((address_space(1))) uint32_t*)g,
                                   (__attribute__((address_space(3))) uint32_t*)l, 16, 0, 0);
}

// ---------------- f32 -> bf16 conversion (6 segments)
struct CvtArgs { const float* src[6]; u16* dst[6]; int n[6]; };

__global__ __launch_bounds__(256) void cvt_bf16(CvtArgs a)
{
  const int seg = blockIdx.y;
  const float* __restrict__ s = a.src[seg];
  u16* __restrict__ d = a.dst[seg];
  const int n = a.n[seg];
  const int i = (blockIdx.x * 256 + threadIdx.x) * 8;
  if (i >= n) return;
  fv4 x0 = *(const fv4*)(s + i);
  fv4 x1 = *(const fv4*)(s + i + 4);
  union { bf8 v; u16 u[8]; } o;
#pragma unroll
  for (int j = 0; j < 4; j++) { o.u[j] = f2bf(x0[j]); o.u[4 + j] = f2bf(x1[j]); }
  *(bf8*)(d + i) = o.v;
}

// ---------------- Projection GEMM (NT), BK=32 double-buffered 2-phase pipeline:
// prologue-stage buf0; per iter {barrier; issue STAGE(buf^1); ds_read+MFMA(buf)}.
// vmcnt(0) drain lands AFTER the MFMA cluster -> staging hidden under compute.
// LDS loop tiles XOR-swizzled (source+read) for conflict-free ds_read_b128.
__global__ __launch_bounds__(256) void proj_gemm(
    const u16* __restrict__ Xq, const u16* __restrict__ Xk, const u16* __restrict__ Xv,
    const u16* __restrict__ Wq, const u16* __restrict__ Wk, const u16* __restrict__ Wv,
    u16* __restrict__ QH, u16* __restrict__ KH, u16* __restrict__ VTB)
{
  __shared__ u16 smem[18432];       // loop: 2 x (A 8KB + B 8KB) = 32KB; epilogue: 4 x 64x72 = 36KB
  const int z = blockIdx.z;
  const u16* X = (z == 0) ? Xq : ((z == 1) ? Xk : Xv);
  const u16* W = (z == 0) ? Wq : ((z == 1) ? Wk : Wv);

  const int tid  = threadIdx.x;
  const int lane = tid & 63;
  const int w    = tid >> 6;
  const int wm   = w >> 1, wn = w & 1;
  const int m0   = blockIdx.x * 128;
  const int n0   = blockIdx.y * 128;
  const int col  = lane & 15, quad = lane >> 4;
  const int sq8  = (quad ^ ((col >> 1) & 3)) * 8;      // swizzled chunk for frag reads

  // staging geometry: each thread stages 2x16B per matrix per K-step (rows 0-63, 64-127)
  const int srow = w * 16 + (lane >> 2);               // 0..63
  const int sc   = ((lane & 3) ^ ((lane >> 3) & 3)) * 8;  // pre-swizzled global chunk
  const size_t gA0 = (size_t)(m0 + srow) * 1024 + sc;
  const size_t gA1 = (size_t)(m0 + 64 + srow) * 1024 + sc;
  const size_t gB0 = (size_t)(n0 + srow) * 1024 + sc;
  const size_t gB1 = (size_t)(n0 + 64 + srow) * 1024 + sc;
  const int ldst = w * 512 + lane * 8;                 // linear LDS dest (u16)

  const f4 zero = {0.f, 0.f, 0.f, 0.f};
  f4 acc[4][4];
#pragma unroll
  for (int i = 0; i < 4; i++)
#pragma unroll
    for (int j = 0; j < 4; j++) acc[i][j] = zero;

  {                                   // prologue: stage t=0 -> buf 0
    gl_lds16(X + gA0, &smem[ldst]);
    gl_lds16(X + gA1, &smem[2048 + ldst]);
    gl_lds16(W + gB0, &smem[4096 + ldst]);
    gl_lds16(W + gB1, &smem[6144 + ldst]);
  }

#pragma unroll 2
  for (int t = 0; t < 32; t++) {
    __syncthreads();                  // buf[t&1] staged; buf[t^1] free to overwrite
    if (t + 1 < 32) {
      const int kn = (t + 1) * 32;
      u16* nb = smem + ((t + 1) & 1) * 8192;
      gl_lds16(X + gA0 + kn, &nb[ldst]);
      gl_lds16(X + gA1 + kn, &nb[2048 + ldst]);
      gl_lds16(W + gB0 + kn, &nb[4096 + ldst]);
      gl_lds16(W + gB1 + kn, &nb[6144 + ldst]);
    }
    const u16* cA = smem + (t & 1) * 8192;
    const u16* cB = cA + 4096;
    bf8 a[4], b[4];
#pragma unroll
    for (int tt = 0; tt < 4; tt++) a[tt] = *(const bf8*)&cA[(wm * 64 + tt * 16 + col) * 32 + sq8];
#pragma unroll
    for (int tt = 0; tt < 4; tt++) b[tt] = *(const bf8*)&cB[(wn * 64 + tt * 16 + col) * 32 + sq8];
#pragma unroll
    for (int mt = 0; mt < 4; mt++)
#pragma unroll
      for (int nt = 0; nt < 4; nt++)
        acc[mt][nt] = __builtin_amdgcn_mfma_f32_16x16x32_bf16(a[mt], b[nt], acc[mt][nt], 0, 0, 0);
  }

  __syncthreads();
  u16* ep = &smem[w * 4608];            // 64 x 72

  if (z == 2) {
#pragma unroll
    for (int mt = 0; mt < 4; mt++)
#pragma unroll
      for (int nt = 0; nt < 4; nt++) {
        u16x4 pk = { f2bf(acc[mt][nt][0]), f2bf(acc[mt][nt][1]),
                     f2bf(acc[mt][nt][2]), f2bf(acc[mt][nt][3]) };
        *(u16x4*)&ep[(nt * 16 + col) * 72 + mt * 16 + quad * 4] = pk;
      }
  } else {
#pragma unroll
    for (int mt = 0; mt < 4; mt++)
#pragma unroll
      for (int nt = 0; nt < 4; nt++)
#pragma unroll
        for (int r = 0; r < 4; r++)
          ep[(mt * 16 + quad * 4 + r) * 72 + nt * 16 + col] = f2bf(acc[mt][nt][r]);
  }

  const int bb = m0 >> 11;
  const int h  = (n0 >> 6) + wn;
  const int bh = bb * 16 + h;

  if (z == 0) {
    const int qbase = (m0 & 2047) + wm * 64;
    u16* dst = QH + ((size_t)bh * SEQ + qbase) * 64;
#pragma unroll
    for (int i = 0; i < 8; i++) {
      const int f  = i * 1024 + lane * 16;
      const int ml = i * 8 + (lane >> 3), nl = (lane & 7) * 8;
      *(bf8*)(dst + (f >> 1)) = *(const bf8*)&ep[ml * 72 + nl];
    }
  } else if (z == 1) {
    const int kt = (((m0 & 2047) >> 6) + wm);
    u16* dst = KH + (((size_t)bh * 32 + kt) << 12);
#pragma unroll
    for (int i = 0; i < 8; i++) {
      const int f   = i * 1024 + lane * 16;
      const int dh  = f >> 12;
      const int klc = (f >> 6) & 63;
      const int dlo = (lane & 3) * 8;
      const int fs  = f ^ (((klc >> 1) & 3) << 4);   // bank swizzle (within 64B row)
      *(bf8*)(dst + (fs >> 1)) = *(const bf8*)&ep[klc * 72 + dh * 32 + dlo];
    }
  } else {
    const int kt = (((m0 & 2047) >> 6) + wm);
    u16* dst = VTB + (((size_t)bh * 32 + kt) << 12);
#pragma unroll
    for (int i = 0; i < 8; i++) {
      const int f   = i * 1024 + lane * 16;
      const int kk  = f >> 12;
      const int d   = (f >> 6) & 63;
      const int klo = (lane & 3) * 8;
      const int fs  = f ^ (((d >> 1) & 3) << 4);     // bank swizzle (within 64B row)
      *(bf8*)(dst + (fs >> 1)) = *(const bf8*)&ep[d * 72 + kk * 32 + klo];
    }
  }
}

// ---------------- masked V mean (dead-row fallback). One wave per (b, e=h*64+d).
__global__ __launch_bounds__(256) void sumv(const u16* __restrict__ VTB,
                                            const float* __restrict__ vmask,
                                            float* __restrict__ fb)
{
  const int w = threadIdx.x >> 6, lane = threadIdx.x & 63;
  const int gw = blockIdx.x * 4 + w;
  const int b = gw >> 10, e = gw & 1023;
  const int h = e >> 6, d = e & 63;
  const int bh = b * 16 + h;
  const float* vm = vmask + b * SEQ;
  const int ksw = (lane & 31) ^ (((d >> 1) & 3) << 3);   // undo VTB swizzle
  float s = 0.f, c = 0.f;
  for (int kt = 0; kt < 32; kt++) {
    const u16 val = VTB[(((size_t)bh * 32 + kt) << 12) + (lane >> 5) * 2048 + d * 32 + ksw];
    const float m = vm[kt * 64 + lane];
    s += m * bf2f(val); c += m;
  }
#pragma unroll
  for (int o = 1; o < 64; o <<= 1) { s += __shfl_xor(s, o); c += __shfl_xor(c, o); }
  if (lane == 0) fb[gw] = s / c;
}

// ---------------- Flash attention, TRANSPOSED form: S^T = K Q^T, O^T = V^T P^T.
// One block per (b,h,qx): grid 1024 (3 resident blocks/CU).
// Heavy-first qx ordering; XCD-clustered (b,h); double-buffered K/V staging;
// swizzled K/V fragment reads (conflict-free); setprio around MFMA clusters.
__global__ __launch_bounds__(256) void attn(
    const u16* __restrict__ QH, const u16* __restrict__ KH, const u16* __restrict__ VTB,
    const float* __restrict__ vmask, const float* __restrict__ qmask,
    const float* __restrict__ fb, float* __restrict__ OUT)
{
  __shared__ float pen[SEQ];            // (1-vm)*1e10*log2e
  __shared__ u16   sK[2][4096];         // [dh2][64key][32d] x2 (swizzled)
  __shared__ u16   sV[2][4096];         // [kk2][64d][32k]   x2 (swizzled)
  __shared__ u16   P[4 * 16 * 72];      // per-wave P^T as [q16][keypad72]

  const int tid = threadIdx.x, lane = tid & 63, w = tid >> 6;
  const int i   = blockIdx.x;           // 0..1023
  const int xcd = i & 7;
  const int j   = i >> 3;               // 0..127
  const int qx  = j >> 2;               // heavy blocks (small qx) dispatch first
  const int bh  = xcd + 8 * (j & 3);    // 4 (b,h) per XCD for K/V L2 locality
  const int b = bh >> 4, h = bh & 15;
  const int col = lane & 15, quad = lane >> 4;
  const int sq8 = (quad ^ ((col >> 1) & 3)) * 8;   // swizzled k-slot for A-frag reads
  const int wb = w * 16 * 72;

  for (int t = tid; t < SEQ; t += 256)
    pen[t] = (1.0f - vmask[b * SEQ + t]) * BIG2F;

  const u16* kbase = KH  + (((size_t)bh * 32) << 12);
  const u16* vbase = VTB + (((size_t)bh * 32) << 12);

  const int q0 = qx * 64;

  // Q as B-frag: n = q = w*16+col, k = d
  bf8 bQ[2];
#pragma unroll
  for (int dh = 0; dh < 2; dh++)
    bQ[dh] = *(const bf8*)&QH[((size_t)bh * SEQ + q0 + w * 16 + col) * 64 + dh * 32 + quad * 8];

  const f4 zero = {0.f, 0.f, 0.f, 0.f};
  f4 accO[4];                           // O^T: [d-tile nt][r]: d = nt*16+quad*4+r, q = w*16+col
  float l_acc = 0.f;                    // softmax denom for q = w*16+col
#pragma unroll
  for (int t = 0; t < 4; t++) accO[t] = zero;

  {                                     // prologue stage -> buf 0
    const size_t toff = ((size_t)qx << 12) + w * 1024 + lane * 8;
    gl_lds16(kbase + toff,       &sK[0][w * 1024]);
    gl_lds16(kbase + toff + 512, &sK[0][w * 1024 + 512]);
    gl_lds16(vbase + toff,       &sV[0][w * 1024]);
    gl_lds16(vbase + toff + 512, &sV[0][w * 1024 + 512]);
  }

  const int ntile = 32 - qx;
  for (int it = 0; it < ntile; it++) {
    __syncthreads();                    // buf[it&1] staged (+ pen ready at it=0)
    if (it + 1 < ntile) {
      const int nb = (it + 1) & 1;
      const size_t toff = ((size_t)(qx + it + 1) << 12) + w * 1024 + lane * 8;
      gl_lds16(kbase + toff,       &sK[nb][w * 1024]);
      gl_lds16(kbase + toff + 512, &sK[nb][w * 1024 + 512]);
      gl_lds16(vbase + toff,       &sV[nb][w * 1024]);
      gl_lds16(vbase + toff + 512, &sV[nb][w * 1024 + 512]);
    }
    const u16* cK = sK[it & 1];
    const u16* cV = sV[it & 1];
    const int k0 = (qx + it) * 64;

    // S^T = K Q^T : A = K (m=key), B = Q (n=q)
    f4 accS[4];
#pragma unroll
    for (int t = 0; t < 4; t++) accS[t] = zero;
    __builtin_amdgcn_s_setprio(1);
#pragma unroll
    for (int nt = 0; nt < 4; nt++)
#pragma unroll
      for (int dh = 0; dh < 2; dh++) {
        bf8 aK = *(const bf8*)&cK[dh * 2048 + (nt * 16 + col) * 32 + sq8];
        accS[nt] = __builtin_amdgcn_mfma_f32_16x16x32_bf16(aK, bQ[dh], accS[nt], 0, 0, 0);
      }
    __builtin_amdgcn_s_setprio(0);

    // p = exp2(s*C2 - pen2 [- causal]) ; accS[nt][r] = S[key=k0+nt*16+quad*4+r][q]
    float p[4][4];
    fv4 pv[4];
#pragma unroll
    for (int nt = 0; nt < 4; nt++) pv[nt] = *(const fv4*)&pen[k0 + nt * 16 + quad * 4];
    if (it == 0) {                      // diagonal tile: key_local <= q_local penalized
#pragma unroll
      for (int nt = 0; nt < 4; nt++)
#pragma unroll
        for (int r = 0; r < 4; r++) {
          float sv = fmaf(accS[nt][r], C2, -pv[nt][r]);
          if (nt * 16 + quad * 4 + r <= w * 16 + col) sv -= BIG2F;
          p[nt][r] = exp2_hw(sv);
        }
    } else {
#pragma unroll
      for (int nt = 0; nt < 4; nt++)
#pragma unroll
        for (int r = 0; r < 4; r++)
          p[nt][r] = exp2_hw(fmaf(accS[nt][r], C2, -pv[nt][r]));
    }
#pragma unroll
    for (int nt = 0; nt < 4; nt++)
      l_acc += (p[nt][0] + p[nt][1]) + (p[nt][2] + p[nt][3]);

    // P^T -> wave-private LDS [q=col][4 consecutive keys] : one b64 per nt
#pragma unroll
    for (int nt = 0; nt < 4; nt++) {
      union { u16x4 v; u16 u[4]; } pk;
      union { __hip_bfloat162 h2; u16 u[2]; } c0, c1;
      float2 f01; f01.x = p[nt][0]; f01.y = p[nt][1];
      float2 f23; f23.x = p[nt][2]; f23.y = p[nt][3];
      c0.h2 = __float22bfloat162_rn(f01);
      c1.h2 = __float22bfloat162_rn(f23);
      pk.u[0] = c0.u[0]; pk.u[1] = c0.u[1]; pk.u[2] = c1.u[0]; pk.u[3] = c1.u[1];
      *(u16x4*)&P[wb + col * 72 + nt * 16 + quad * 4] = pk.v;
    }

    // O^T += V^T P^T : A = V^T (m=d), B = P^T (n=q, k=key)
    __builtin_amdgcn_s_setprio(1);
#pragma unroll
    for (int kk = 0; kk < 2; kk++) {
      bf8 bP = *(const bf8*)&P[wb + col * 72 + kk * 32 + quad * 8];
#pragma unroll
      for (int nt = 0; nt < 4; nt++) {
        bf8 aV = *(const bf8*)&cV[kk * 2048 + (nt * 16 + col) * 32 + sq8];
        accO[nt] = __builtin_amdgcn_mfma_f32_16x16x32_bf16(aV, bP, accO[nt], 0, 0, 0);
      }
    }
    __builtin_amdgcn_s_setprio(0);
  }

  // epilogue: reduce l over quads (lane bits 4-5), divide, q_mask, dwordx4 stores
  float l = l_acc;
  l += __shfl_xor(l, 16); l += __shfl_xor(l, 32);
  const int q = q0 + w * 16 + col;
  const float qm = qmask[b * SEQ + q];
  float* op = OUT + (size_t)(b * SEQ + q) * EMB + h * 64;
  if (l == 0.0f) {                      // dead row: uniform masked-average fallback
#pragma unroll
    for (int nt = 0; nt < 4; nt++) {
      fv4 f = *(const fv4*)&fb[b * 1024 + h * 64 + nt * 16 + quad * 4];
      f *= qm;
      *(fv4*)(op + nt * 16 + quad * 4) = f;
    }
  } else {
    const float s = qm / l;
#pragma unroll
    for (int nt = 0; nt < 4; nt++) {
      fv4 f = { accO[nt][0] * s, accO[nt][1] * s, accO[nt][2] * s, accO[nt][3] * s };
      *(fv4*)(op + nt * 16 + quad * 4) = f;
    }
  }
}

extern "C" void kernel_launch(void* const* d_in, const int* in_sizes, int n_in,
                              void* d_out, int out_size, void* d_ws, size_t ws_size,
                              hipStream_t stream)
{
  const float* q  = (const float*)d_in[0];
  const float* k  = (const float*)d_in[1];
  const float* v  = (const float*)d_in[2];
  const float* vm = (const float*)d_in[3];
  const float* qm = (const float*)d_in[4];
  const float* Wq = (const float*)d_in[5];
  const float* Wk = (const float*)d_in[6];
  const float* Wv = (const float*)d_in[7];
  float* out = (float*)d_out;

  const size_t NBIG = (size_t)B_ * SEQ * EMB;   // 4 Mi
  const size_t NW   = (size_t)EMB * EMB;        // 1 Mi

  u16* qb  = (u16*)d_ws;
  u16* kb  = qb  + NBIG;
  u16* vb  = kb  + NBIG;
  u16* Wqb = vb  + NBIG;
  u16* Wkb = Wqb + NW;
  u16* Wvb = Wkb + NW;
  u16* QH  = Wvb + NW;
  u16* KH  = QH  + NBIG;
  u16* VTB = KH  + NBIG;
  float* fb = (float*)(VTB + NBIG);             // [2][1024] f32

  CvtArgs ca;
  ca.src[0] = q;  ca.dst[0] = qb;  ca.n[0] = (int)NBIG;
  ca.src[1] = k;  ca.dst[1] = kb;  ca.n[1] = (int)NBIG;
  ca.src[2] = v;  ca.dst[2] = vb;  ca.n[2] = (int)NBIG;
  ca.src[3] = Wq; ca.dst[3] = Wqb; ca.n[3] = (int)NW;
  ca.src[4] = Wk; ca.dst[4] = Wkb; ca.n[4] = (int)NW;
  ca.src[5] = Wv; ca.dst[5] = Wvb; ca.n[5] = (int)NW;

  cvt_bf16<<<dim3((unsigned)(NBIG / 8 / 256), 6, 1), 256, 0, stream>>>(ca);
  proj_gemm<<<dim3(32, 8, 3), 256, 0, stream>>>(qb, kb, vb, Wqb, Wkb, Wvb, QH, KH, VTB);
  sumv<<<dim3(512, 1, 1), 256, 0, stream>>>(VTB, vm, fb);
  attn<<<dim3(1024, 1, 1), 256, 0, stream>>>(QH, KH, VTB, vm, qm, fb, out);
}

// Round 3
// 178.666 us; speedup vs baseline: 1.1204x; 1.0504x over previous
//
#include <hip/hip_runtime.h>
#include <hip/hip_bf16.h>
#include <stdint.h>

// B=2, L=2048, E=1024, H=16, Dh=64. f32 in/out; bf16 MFMA compute.
// Layouts (workspace, produced by proj_gemm):
//   QH [b,h,q,64d]               : q-row = 128B contiguous
//   KH [b,h,kt][dh2][64k][32d]   : 8KB/tile, XOR-swizzled: byte ^= ((key>>1)&3)<<4
//   VTB[b,h,kt][kk2][64d][32k]   : 8KB/tile, XOR-swizzled: byte ^= ((d>>1)&3)<<4
// All LDS tiles staged via global_load_lds are swizzled on the GLOBAL source +
// the ds_read side, never the LDS dest (global_load_lds dest must stay linear).
#define B_    2
#define SEQ   2048
#define EMB   1024
#define BIGF  1e10f
#define LOG2E 1.4426950408889634f
#define BIG2F (1e10f * LOG2E)
#define C2    (0.125f * LOG2E)

typedef unsigned short u16;
typedef __attribute__((ext_vector_type(4))) u16      u16x4;
typedef __attribute__((ext_vector_type(8))) short    bf8;   // MFMA A/B frag (16B)
typedef __attribute__((ext_vector_type(4))) float    f4;    // MFMA C/D frag
typedef __attribute__((ext_vector_type(4))) float    fv4;

__device__ inline float bf2f(u16 u){ union{uint32_t i; float f;} v; v.i = ((uint32_t)u) << 16; return v.f; }
__device__ inline u16 f2bf(float f){ union{float f; uint32_t i;} v; v.f = f;
                                     uint32_t r = v.i + 0x7fffu + ((v.i >> 16) & 1u); return (u16)(r >> 16); }
__device__ inline float exp2_hw(float x){ float r; asm("v_exp_f32 %0, %1" : "=v"(r) : "v"(x)); return r; }

__device__ inline void gl_lds16(const void* g, void* l){
  __builtin_amdgcn_global_load_lds((const __attribute__((address_space(1))) uint32_t*)g,
                                   (__attribute__((address_space(3))) uint32_t*)l, 16, 0, 0);
}

// ---------------- f32 -> bf16 conversion (6 segments)
struct CvtArgs { const float* src[6]; u16* dst[6]; int n[6]; };

__global__ __launch_bounds__(256) void cvt_bf16(CvtArgs a)
{
  const int seg = blockIdx.y;
  const float* __restrict__ s = a.src[seg];
  u16* __restrict__ d = a.dst[seg];
  const int n = a.n[seg];
  const int i = (blockIdx.x * 256 + threadIdx.x) * 8;
  if (i >= n) return;
  fv4 x0 = *(const fv4*)(s + i);
  fv4 x1 = *(const fv4*)(s + i + 4);
  union { bf8 v; u16 u[8]; } o;
#pragma unroll
  for (int j = 0; j < 4; j++) { o.u[j] = f2bf(x0[j]); o.u[4 + j] = f2bf(x1[j]); }
  *(bf8*)(d + i) = o.v;
}

// ---------------- Projection GEMM (NT), BK=32, 2-deep counted-vmcnt pipeline:
// prologue stages tiles t0,t1; per iter {vmcnt(4); barrier; ds_read buf[t];
// lgkmcnt(0); barrier; STAGE(buf[t], t+2); MFMA}. No vmcnt(0) drain in the
// main loop: loads stay in flight across barriers (T3+T4 mechanism).
// LDS loop tiles XOR-swizzled (source+read) for conflict-free ds_read_b128.
__global__ __launch_bounds__(256) void proj_gemm(
    const u16* __restrict__ Xq, const u16* __restrict__ Xk, const u16* __restrict__ Xv,
    const u16* __restrict__ Wq, const u16* __restrict__ Wk, const u16* __restrict__ Wv,
    u16* __restrict__ QH, u16* __restrict__ KH, u16* __restrict__ VTB)
{
  __shared__ u16 smem[18432];       // loop: 2 x (A 8KB + B 8KB) = 32KB; epilogue: 4 x 64x72 = 36KB
  const int z = blockIdx.z;
  const u16* X = (z == 0) ? Xq : ((z == 1) ? Xk : Xv);
  const u16* W = (z == 0) ? Wq : ((z == 1) ? Wk : Wv);

  const int tid  = threadIdx.x;
  const int lane = tid & 63;
  const int w    = tid >> 6;
  const int wm   = w >> 1, wn = w & 1;
  const int m0   = blockIdx.x * 128;
  const int n0   = blockIdx.y * 128;
  const int col  = lane & 15, quad = lane >> 4;
  const int sq8  = (quad ^ ((col >> 1) & 3)) * 8;      // swizzled chunk for frag reads

  // staging geometry: each thread stages 2x16B per matrix per K-step (rows 0-63, 64-127)
  const int srow = w * 16 + (lane >> 2);               // 0..63
  const int sc   = ((lane & 3) ^ ((lane >> 3) & 3)) * 8;  // pre-swizzled global chunk
  const size_t gA0 = (size_t)(m0 + srow) * 1024 + sc;
  const size_t gA1 = (size_t)(m0 + 64 + srow) * 1024 + sc;
  const size_t gB0 = (size_t)(n0 + srow) * 1024 + sc;
  const size_t gB1 = (size_t)(n0 + 64 + srow) * 1024 + sc;
  const int ldst = w * 512 + lane * 8;                 // linear LDS dest (u16)

#define PSTAGE(nb, kn) do { \
    gl_lds16(X + gA0 + (kn), &(nb)[ldst]); \
    gl_lds16(X + gA1 + (kn), &(nb)[2048 + ldst]); \
    gl_lds16(W + gB0 + (kn), &(nb)[4096 + ldst]); \
    gl_lds16(W + gB1 + (kn), &(nb)[6144 + ldst]); \
  } while (0)

  const f4 zero = {0.f, 0.f, 0.f, 0.f};
  f4 acc[4][4];
#pragma unroll
  for (int i = 0; i < 4; i++)
#pragma unroll
    for (int j = 0; j < 4; j++) acc[i][j] = zero;

  // prologue: 2 tiles in flight (8 vmem ops/wave outstanding)
  PSTAGE(smem, 0);
  PSTAGE((smem + 8192), 32);

#pragma unroll 2
  for (int t = 0; t < 31; t++) {
    // current tile's 4 loads done; next tile's 4 stay in flight
    asm volatile("s_waitcnt vmcnt(4)" ::: "memory");
    __builtin_amdgcn_s_barrier();
    __builtin_amdgcn_sched_barrier(0);
    const u16* cA = smem + (t & 1) * 8192;
    const u16* cB = cA + 4096;
    bf8 a[4], b[4];
#pragma unroll
    for (int tt = 0; tt < 4; tt++) a[tt] = *(const bf8*)&cA[(wm * 64 + tt * 16 + col) * 32 + sq8];
#pragma unroll
    for (int tt = 0; tt < 4; tt++) b[tt] = *(const bf8*)&cB[(wn * 64 + tt * 16 + col) * 32 + sq8];
    asm volatile("s_waitcnt lgkmcnt(0)" ::: "memory");
    __builtin_amdgcn_sched_barrier(0);
    __builtin_amdgcn_s_barrier();       // all waves done reading buf[t&1]
    if (t < 30) {                       // restage the just-freed buffer, 2 ahead
      u16* nb = smem + (t & 1) * 8192;
      PSTAGE(nb, (t + 2) * 32);
    }
    __builtin_amdgcn_s_setprio(1);
#pragma unroll
    for (int mt = 0; mt < 4; mt++)
#pragma unroll
      for (int nt = 0; nt < 4; nt++)
        acc[mt][nt] = __builtin_amdgcn_mfma_f32_16x16x32_bf16(a[mt], b[nt], acc[mt][nt], 0, 0, 0);
    __builtin_amdgcn_s_setprio(0);
  }
  {                                     // peeled last tile (t = 31, buf1, drain)
    asm volatile("s_waitcnt vmcnt(0)" ::: "memory");
    __builtin_amdgcn_s_barrier();
    __builtin_amdgcn_sched_barrier(0);
    const u16* cA = smem + 8192;
    const u16* cB = cA + 4096;
    bf8 a[4], b[4];
#pragma unroll
    for (int tt = 0; tt < 4; tt++) a[tt] = *(const bf8*)&cA[(wm * 64 + tt * 16 + col) * 32 + sq8];
#pragma unroll
    for (int tt = 0; tt < 4; tt++) b[tt] = *(const bf8*)&cB[(wn * 64 + tt * 16 + col) * 32 + sq8];
    __builtin_amdgcn_s_setprio(1);
#pragma unroll
    for (int mt = 0; mt < 4; mt++)
#pragma unroll
      for (int nt = 0; nt < 4; nt++)
        acc[mt][nt] = __builtin_amdgcn_mfma_f32_16x16x32_bf16(a[mt], b[nt], acc[mt][nt], 0, 0, 0);
    __builtin_amdgcn_s_setprio(0);
  }
#undef PSTAGE

  __syncthreads();
  u16* ep = &smem[w * 4608];            // 64 x 72

  if (z == 2) {
#pragma unroll
    for (int mt = 0; mt < 4; mt++)
#pragma unroll
      for (int nt = 0; nt < 4; nt++) {
        u16x4 pk = { f2bf(acc[mt][nt][0]), f2bf(acc[mt][nt][1]),
                     f2bf(acc[mt][nt][2]), f2bf(acc[mt][nt][3]) };
        *(u16x4*)&ep[(nt * 16 + col) * 72 + mt * 16 + quad * 4] = pk;
      }
  } else {
#pragma unroll
    for (int mt = 0; mt < 4; mt++)
#pragma unroll
      for (int nt = 0; nt < 4; nt++)
#pragma unroll
        for (int r = 0; r < 4; r++)
          ep[(mt * 16 + quad * 4 + r) * 72 + nt * 16 + col] = f2bf(acc[mt][nt][r]);
  }

  const int bb = m0 >> 11;
  const int h  = (n0 >> 6) + wn;
  const int bh = bb * 16 + h;

  if (z == 0) {
    const int qbase = (m0 & 2047) + wm * 64;
    u16* dst = QH + ((size_t)bh * SEQ + qbase) * 64;
#pragma unroll
    for (int i = 0; i < 8; i++) {
      const int f  = i * 1024 + lane * 16;
      const int ml = i * 8 + (lane >> 3), nl = (lane & 7) * 8;
      *(bf8*)(dst + (f >> 1)) = *(const bf8*)&ep[ml * 72 + nl];
    }
  } else if (z == 1) {
    const int kt = (((m0 & 2047) >> 6) + wm);
    u16* dst = KH + (((size_t)bh * 32 + kt) << 12);
#pragma unroll
    for (int i = 0; i < 8; i++) {
      const int f   = i * 1024 + lane * 16;
      const int dh  = f >> 12;
      const int klc = (f >> 6) & 63;
      const int dlo = (lane & 3) * 8;
      const int fs  = f ^ (((klc >> 1) & 3) << 4);   // bank swizzle (within 64B row)
      *(bf8*)(dst + (fs >> 1)) = *(const bf8*)&ep[klc * 72 + dh * 32 + dlo];
    }
  } else {
    const int kt = (((m0 & 2047) >> 6) + wm);
    u16* dst = VTB + (((size_t)bh * 32 + kt) << 12);
#pragma unroll
    for (int i = 0; i < 8; i++) {
      const int f   = i * 1024 + lane * 16;
      const int kk  = f >> 12;
      const int d   = (f >> 6) & 63;
      const int klo = (lane & 3) * 8;
      const int fs  = f ^ (((d >> 1) & 3) << 4);     // bank swizzle (within 64B row)
      *(bf8*)(dst + (fs >> 1)) = *(const bf8*)&ep[d * 72 + kk * 32 + klo];
    }
  }
}

// ---------------- masked V mean (dead-row fallback). One wave per (b, e=h*64+d).
__global__ __launch_bounds__(256) void sumv(const u16* __restrict__ VTB,
                                            const float* __restrict__ vmask,
                                            float* __restrict__ fb)
{
  const int w = threadIdx.x >> 6, lane = threadIdx.x & 63;
  const int gw = blockIdx.x * 4 + w;
  const int b = gw >> 10, e = gw & 1023;
  const int h = e >> 6, d = e & 63;
  const int bh = b * 16 + h;
  const float* vm = vmask + b * SEQ;
  const int ksw = (lane & 31) ^ (((d >> 1) & 3) << 3);   // undo VTB swizzle
  float s = 0.f, c = 0.f;
  for (int kt = 0; kt < 32; kt++) {
    const u16 val = VTB[(((size_t)bh * 32 + kt) << 12) + (lane >> 5) * 2048 + d * 32 + ksw];
    const float m = vm[kt * 64 + lane];
    s += m * bf2f(val); c += m;
  }
#pragma unroll
  for (int o = 1; o < 64; o <<= 1) { s += __shfl_xor(s, o); c += __shfl_xor(c, o); }
  if (lane == 0) fb[gw] = s / c;
}

// ---------------- Flash attention, TRANSPOSED form: S^T = K Q^T, O^T = V^T P^T.
// One block per (b,h,qx): grid 1024 (3 resident blocks/CU).
// Heavy-first qx ordering; XCD-clustered (b,h); double-buffered K/V staging;
// swizzled K/V fragment reads (conflict-free); setprio around MFMA clusters.
__global__ __launch_bounds__(256) void attn(
    const u16* __restrict__ QH, const u16* __restrict__ KH, const u16* __restrict__ VTB,
    const float* __restrict__ vmask, const float* __restrict__ qmask,
    const float* __restrict__ fb, float* __restrict__ OUT)
{
  __shared__ float pen[SEQ];            // (1-vm)*1e10*log2e
  __shared__ u16   sK[2][4096];         // [dh2][64key][32d] x2 (swizzled)
  __shared__ u16   sV[2][4096];         // [kk2][64d][32k]   x2 (swizzled)
  __shared__ u16   P[4 * 16 * 72];      // per-wave P^T as [q16][keypad72]

  const int tid = threadIdx.x, lane = tid & 63, w = tid >> 6;
  const int i   = blockIdx.x;           // 0..1023
  const int xcd = i & 7;
  const int j   = i >> 3;               // 0..127
  const int qx  = j >> 2;               // heavy blocks (small qx) dispatch first
  const int bh  = xcd + 8 * (j & 3);    // 4 (b,h) per XCD for K/V L2 locality
  const int b = bh >> 4, h = bh & 15;
  const int col = lane & 15, quad = lane >> 4;
  const int sq8 = (quad ^ ((col >> 1) & 3)) * 8;   // swizzled k-slot for A-frag reads
  const int wb = w * 16 * 72;

  for (int t = tid; t < SEQ; t += 256)
    pen[t] = (1.0f - vmask[b * SEQ + t]) * BIG2F;

  const u16* kbase = KH  + (((size_t)bh * 32) << 12);
  const u16* vbase = VTB + (((size_t)bh * 32) << 12);

  const int q0 = qx * 64;

  // Q as B-frag: n = q = w*16+col, k = d
  bf8 bQ[2];
#pragma unroll
  for (int dh = 0; dh < 2; dh++)
    bQ[dh] = *(const bf8*)&QH[((size_t)bh * SEQ + q0 + w * 16 + col) * 64 + dh * 32 + quad * 8];

  const f4 zero = {0.f, 0.f, 0.f, 0.f};
  f4 accO[4];                           // O^T: [d-tile nt][r]: d = nt*16+quad*4+r, q = w*16+col
  float l_acc = 0.f;                    // softmax denom for q = w*16+col
#pragma unroll
  for (int t = 0; t < 4; t++) accO[t] = zero;

  {                                     // prologue stage -> buf 0
    const size_t toff = ((size_t)qx << 12) + w * 1024 + lane * 8;
    gl_lds16(kbase + toff,       &sK[0][w * 1024]);
    gl_lds16(kbase + toff + 512, &sK[0][w * 1024 + 512]);
    gl_lds16(vbase + toff,       &sV[0][w * 1024]);
    gl_lds16(vbase + toff + 512, &sV[0][w * 1024 + 512]);
  }

  const int ntile = 32 - qx;
  for (int it = 0; it < ntile; it++) {
    __syncthreads();                    // buf[it&1] staged (+ pen ready at it=0)
    if (it + 1 < ntile) {
      const int nb = (it + 1) & 1;
      const size_t toff = ((size_t)(qx + it + 1) << 12) + w * 1024 + lane * 8;
      gl_lds16(kbase + toff,       &sK[nb][w * 1024]);
      gl_lds16(kbase + toff + 512, &sK[nb][w * 1024 + 512]);
      gl_lds16(vbase + toff,       &sV[nb][w * 1024]);
      gl_lds16(vbase + toff + 512, &sV[nb][w * 1024 + 512]);
    }
    const u16* cK = sK[it & 1];
    const u16* cV = sV[it & 1];
    const int k0 = (qx + it) * 64;

    // S^T = K Q^T : A = K (m=key), B = Q (n=q)
    f4 accS[4];
#pragma unroll
    for (int t = 0; t < 4; t++) accS[t] = zero;
    __builtin_amdgcn_s_setprio(1);
#pragma unroll
    for (int nt = 0; nt < 4; nt++)
#pragma unroll
      for (int dh = 0; dh < 2; dh++) {
        bf8 aK = *(const bf8*)&cK[dh * 2048 + (nt * 16 + col) * 32 + sq8];
        accS[nt] = __builtin_amdgcn_mfma_f32_16x16x32_bf16(aK, bQ[dh], accS[nt], 0, 0, 0);
      }
    __builtin_amdgcn_s_setprio(0);

    // p = exp2(s*C2 - pen2 [- causal]) ; accS[nt][r] = S[key=k0+nt*16+quad*4+r][q]
    float p[4][4];
    fv4 pv[4];
#pragma unroll
    for (int nt = 0; nt < 4; nt++) pv[nt] = *(const fv4*)&pen[k0 + nt * 16 + quad * 4];
    if (it == 0) {                      // diagonal tile: key_local <= q_local penalized
#pragma unroll
      for (int nt = 0; nt < 4; nt++)
#pragma unroll
        for (int r = 0; r < 4; r++) {
          float sv = fmaf(accS[nt][r], C2, -pv[nt][r]);
          if (nt * 16 + quad * 4 + r <= w * 16 + col) sv -= BIG2F;
          p[nt][r] = exp2_hw(sv);
        }
    } else {
#pragma unroll
      for (int nt = 0; nt < 4; nt++)
#pragma unroll
        for (int r = 0; r < 4; r++)
          p[nt][r] = exp2_hw(fmaf(accS[nt][r], C2, -pv[nt][r]));
    }
#pragma unroll
    for (int nt = 0; nt < 4; nt++)
      l_acc += (p[nt][0] + p[nt][1]) + (p[nt][2] + p[nt][3]);

    // P^T -> wave-private LDS [q=col][4 consecutive keys] : one b64 per nt
#pragma unroll
    for (int nt = 0; nt < 4; nt++) {
      union { u16x4 v; u16 u[4]; } pk;
      union { __hip_bfloat162 h2; u16 u[2]; } c0, c1;
      float2 f01; f01.x = p[nt][0]; f01.y = p[nt][1];
      float2 f23; f23.x = p[nt][2]; f23.y = p[nt][3];
      c0.h2 = __float22bfloat162_rn(f01);
      c1.h2 = __float22bfloat162_rn(f23);
      pk.u[0] = c0.u[0]; pk.u[1] = c0.u[1]; pk.u[2] = c1.u[0]; pk.u[3] = c1.u[1];
      *(u16x4*)&P[wb + col * 72 + nt * 16 + quad * 4] = pk.v;
    }

    // O^T += V^T P^T : A = V^T (m=d), B = P^T (n=q, k=key)
    __builtin_amdgcn_s_setprio(1);
#pragma unroll
    for (int kk = 0; kk < 2; kk++) {
      bf8 bP = *(const bf8*)&P[wb + col * 72 + kk * 32 + quad * 8];
#pragma unroll
      for (int nt = 0; nt < 4; nt++) {
        bf8 aV = *(const bf8*)&cV[kk * 2048 + (nt * 16 + col) * 32 + sq8];
        accO[nt] = __builtin_amdgcn_mfma_f32_16x16x32_bf16(aV, bP, accO[nt], 0, 0, 0);
      }
    }
    __builtin_amdgcn_s_setprio(0);
  }

  // epilogue: reduce l over quads (lane bits 4-5), divide, q_mask, dwordx4 stores
  float l = l_acc;
  l += __shfl_xor(l, 16); l += __shfl_xor(l, 32);
  const int q = q0 + w * 16 + col;
  const float qm = qmask[b * SEQ + q];
  float* op = OUT + (size_t)(b * SEQ + q) * EMB + h * 64;
  if (l == 0.0f) {                      // dead row: uniform masked-average fallback
#pragma unroll
    for (int nt = 0; nt < 4; nt++) {
      fv4 f = *(const fv4*)&fb[b * 1024 + h * 64 + nt * 16 + quad * 4];
      f *= qm;
      *(fv4*)(op + nt * 16 + quad * 4) = f;
    }
  } else {
    const float s = qm / l;
#pragma unroll
    for (int nt = 0; nt < 4; nt++) {
      fv4 f = { accO[nt][0] * s, accO[nt][1] * s, accO[nt][2] * s, accO[nt][3] * s };
      *(fv4*)(op + nt * 16 + quad * 4) = f;
    }
  }
}

extern "C" void kernel_launch(void* const* d_in, const int* in_sizes, int n_in,
                              void* d_out, int out_size, void* d_ws, size_t ws_size,
                              hipStream_t stream)
{
  const float* q  = (const float*)d_in[0];
  const float* k  = (const float*)d_in[1];
  const float* v  = (const float*)d_in[2];
  const float* vm = (const float*)d_in[3];
  const float* qm = (const float*)d_in[4];
  const float* Wq = (const float*)d_in[5];
  const float* Wk = (const float*)d_in[6];
  const float* Wv = (const float*)d_in[7];
  float* out = (float*)d_out;

  const size_t NBIG = (size_t)B_ * SEQ * EMB;   // 4 Mi
  const size_t NW   = (size_t)EMB * EMB;        // 1 Mi

  u16* qb  = (u16*)d_ws;
  u16* kb  = qb  + NBIG;
  u16* vb  = kb  + NBIG;
  u16* Wqb = vb  + NBIG;
  u16* Wkb = Wqb + NW;
  u16* Wvb = Wkb + NW;
  u16* QH  = Wvb + NW;
  u16* KH  = QH  + NBIG;
  u16* VTB = KH  + NBIG;
  float* fb = (float*)(VTB + NBIG);             // [2][1024] f32

  CvtArgs ca;
  ca.src[0] = q;  ca.dst[0] = qb;  ca.n[0] = (int)NBIG;
  ca.src[1] = k;  ca.dst[1] = kb;  ca.n[1] = (int)NBIG;
  ca.src[2] = v;  ca.dst[2] = vb;  ca.n[2] = (int)NBIG;
  ca.src[3] = Wq; ca.dst[3] = Wqb; ca.n[3] = (int)NW;
  ca.src[4] = Wk; ca.dst[4] = Wkb; ca.n[4] = (int)NW;
  ca.src[5] = Wv; ca.dst[5] = Wvb; ca.n[5] = (int)NW;

  cvt_bf16<<<dim3((unsigned)(NBIG / 8 / 256), 6, 1), 256, 0, stream>>>(ca);
  proj_gemm<<<dim3(32, 8, 3), 256, 0, stream>>>(qb, kb, vb, Wqb, Wkb, Wvb, QH, KH, VTB);
  sumv<<<dim3(512, 1, 1), 256, 0, stream>>>(VTB, vm, fb);
  attn<<<dim3(1024, 1, 1), 256, 0, stream>>>(QH, KH, VTB, vm, qm, fb, out);
}

// Round 4
// 177.995 us; speedup vs baseline: 1.1246x; 1.0038x over previous
//
#include <hip/hip_runtime.h>
#include <hip/hip_bf16.h>
#include <stdint.h>

// B=2, L=2048, E=1024, H=16, Dh=64. f32 in/out; bf16 MFMA compute.
// Layouts (workspace, produced by proj_gemm):
//   QH [b,h,q,64d]               : q-row = 128B contiguous
//   KH [b,h,kt][dh2][64k][32d]   : 8KB/tile, XOR-swizzled: byte ^= ((key>>1)&3)<<4
//   VTB[b,h,kt][kk2][64d][32k]   : 8KB/tile, XOR-swizzled: byte ^= ((d>>1)&3)<<4
// All LDS tiles staged via global_load_lds are swizzled on the GLOBAL source +
// the ds_read side, never the LDS dest (global_load_lds dest must stay linear).
#define B_    2
#define SEQ   2048
#define EMB   1024
#define BIGF  1e10f
#define LOG2E 1.4426950408889634f
#define BIG2F (1e10f * LOG2E)
#define C2    (0.125f * LOG2E)

typedef unsigned short u16;
typedef __attribute__((ext_vector_type(4))) u16      u16x4;
typedef __attribute__((ext_vector_type(8))) short    bf8;   // MFMA A/B frag (16B)
typedef __attribute__((ext_vector_type(4))) float    f4;    // MFMA C/D frag
typedef __attribute__((ext_vector_type(4))) float    fv4;

__device__ inline float bf2f(u16 u){ union{uint32_t i; float f;} v; v.i = ((uint32_t)u) << 16; return v.f; }
__device__ inline u16 f2bf(float f){ union{float f; uint32_t i;} v; v.f = f;
                                     uint32_t r = v.i + 0x7fffu + ((v.i >> 16) & 1u); return (u16)(r >> 16); }
__device__ inline float exp2_hw(float x){ float r; asm("v_exp_f32 %0, %1" : "=v"(r) : "v"(x)); return r; }

__device__ inline void gl_lds16(const void* g, void* l){
  __builtin_amdgcn_global_load_lds((const __attribute__((address_space(1))) uint32_t*)g,
                                   (__attribute__((address_space(3))) uint32_t*)l, 16, 0, 0);
}

// ---------------- f32 -> bf16 conversion (6 segments)
struct CvtArgs { const float* src[6]; u16* dst[6]; int n[6]; };

__global__ __launch_bounds__(256) void cvt_bf16(CvtArgs a)
{
  const int seg = blockIdx.y;
  const float* __restrict__ s = a.src[seg];
  u16* __restrict__ d = a.dst[seg];
  const int n = a.n[seg];
  const int i = (blockIdx.x * 256 + threadIdx.x) * 8;
  if (i >= n) return;
  fv4 x0 = *(const fv4*)(s + i);
  fv4 x1 = *(const fv4*)(s + i + 4);
  union { bf8 v; u16 u[8]; } o;
#pragma unroll
  for (int j = 0; j < 4; j++) { o.u[j] = f2bf(x0[j]); o.u[4 + j] = f2bf(x1[j]); }
  *(bf8*)(d + i) = o.v;
}

// ---------------- Projection GEMM (NT), BK=32, 3-deep counted-vmcnt pipeline:
// prologue stages tiles 0,1,2; steady state waits vmcnt(8) (tiles t+1,t+2 in
// flight = 2 full phases of latency cover), tail peeled vmcnt(8/4/0).
// LDS: 3 x 16KB loop buffers (48KB; occupancy is grid-limited at 3 blk/CU so
// the extra buffer is free); epilogue reuses 36KB of the same smem.
__global__ __launch_bounds__(256) void proj_gemm(
    const u16* __restrict__ Xq, const u16* __restrict__ Xk, const u16* __restrict__ Xv,
    const u16* __restrict__ Wq, const u16* __restrict__ Wk, const u16* __restrict__ Wv,
    u16* __restrict__ QH, u16* __restrict__ KH, u16* __restrict__ VTB)
{
  __shared__ u16 smem[24576];       // loop: 3 x (A 8KB + B 8KB) = 48KB; epilogue: 36KB
  const int z = blockIdx.z;
  const u16* X = (z == 0) ? Xq : ((z == 1) ? Xk : Xv);
  const u16* W = (z == 0) ? Wq : ((z == 1) ? Wk : Wv);

  const int tid  = threadIdx.x;
  const int lane = tid & 63;
  const int w    = tid >> 6;
  const int wm   = w >> 1, wn = w & 1;
  const int m0   = blockIdx.x * 128;
  const int n0   = blockIdx.y * 128;
  const int col  = lane & 15, quad = lane >> 4;
  const int sq8  = (quad ^ ((col >> 1) & 3)) * 8;      // swizzled chunk for frag reads

  // staging geometry: each thread stages 2x16B per matrix per K-step (rows 0-63, 64-127)
  const int srow = w * 16 + (lane >> 2);               // 0..63
  const int sc   = ((lane & 3) ^ ((lane >> 3) & 3)) * 8;  // pre-swizzled global chunk
  const size_t gA0 = (size_t)(m0 + srow) * 1024 + sc;
  const size_t gA1 = (size_t)(m0 + 64 + srow) * 1024 + sc;
  const size_t gB0 = (size_t)(n0 + srow) * 1024 + sc;
  const size_t gB1 = (size_t)(n0 + 64 + srow) * 1024 + sc;
  const int ldst = w * 512 + lane * 8;                 // linear LDS dest (u16)

#define PSTAGE(nb, kn) do { \
    gl_lds16(X + gA0 + (kn), &(nb)[ldst]); \
    gl_lds16(X + gA1 + (kn), &(nb)[2048 + ldst]); \
    gl_lds16(W + gB0 + (kn), &(nb)[4096 + ldst]); \
    gl_lds16(W + gB1 + (kn), &(nb)[6144 + ldst]); \
  } while (0)

  const f4 zero = {0.f, 0.f, 0.f, 0.f};
  f4 acc[4][4];
#pragma unroll
  for (int i = 0; i < 4; i++)
#pragma unroll
    for (int j = 0; j < 4; j++) acc[i][j] = zero;

  // prologue: 3 tiles in flight (12 vmem ops/wave outstanding)
  PSTAGE(smem, 0);
  PSTAGE((smem + 8192), 32);
  PSTAGE((smem + 16384), 64);

#define PBODY(T, BASE, DOSTAGE) do { \
    __builtin_amdgcn_s_barrier(); \
    __builtin_amdgcn_sched_barrier(0); \
    const u16* cA_ = (BASE); \
    const u16* cB_ = (BASE) + 4096; \
    bf8 a_[4], b_[4]; \
    _Pragma("unroll") \
    for (int tt = 0; tt < 4; tt++) a_[tt] = *(const bf8*)&cA_[(wm * 64 + tt * 16 + col) * 32 + sq8]; \
    _Pragma("unroll") \
    for (int tt = 0; tt < 4; tt++) b_[tt] = *(const bf8*)&cB_[(wn * 64 + tt * 16 + col) * 32 + sq8]; \
    asm volatile("s_waitcnt lgkmcnt(0)" ::: "memory"); \
    __builtin_amdgcn_sched_barrier(0); \
    __builtin_amdgcn_s_barrier(); \
    if (DOSTAGE) { PSTAGE((BASE), ((T) + 3) * 32); } \
    __builtin_amdgcn_s_setprio(1); \
    _Pragma("unroll") \
    for (int mt = 0; mt < 4; mt++) \
      _Pragma("unroll") \
      for (int nt = 0; nt < 4; nt++) \
        acc[mt][nt] = __builtin_amdgcn_mfma_f32_16x16x32_bf16(a_[mt], b_[nt], acc[mt][nt], 0, 0, 0); \
    __builtin_amdgcn_s_setprio(0); \
  } while (0)

  for (int t3 = 0; t3 < 27; t3 += 3) {
    asm volatile("s_waitcnt vmcnt(8)" ::: "memory"); PBODY(t3 + 0, smem, 1);
    asm volatile("s_waitcnt vmcnt(8)" ::: "memory"); PBODY(t3 + 1, (smem + 8192), 1);
    asm volatile("s_waitcnt vmcnt(8)" ::: "memory"); PBODY(t3 + 2, (smem + 16384), 1);
  }
  asm volatile("s_waitcnt vmcnt(8)" ::: "memory"); PBODY(27, smem, 1);
  asm volatile("s_waitcnt vmcnt(8)" ::: "memory"); PBODY(28, (smem + 8192), 1);
  asm volatile("s_waitcnt vmcnt(8)" ::: "memory"); PBODY(29, (smem + 16384), 0);
  asm volatile("s_waitcnt vmcnt(4)" ::: "memory"); PBODY(30, smem, 0);
  asm volatile("s_waitcnt vmcnt(0)" ::: "memory"); PBODY(31, (smem + 8192), 0);
#undef PBODY
#undef PSTAGE

  __syncthreads();
  u16* ep = &smem[w * 4608];            // 64 x 72

  if (z == 2) {
#pragma unroll
    for (int mt = 0; mt < 4; mt++)
#pragma unroll
      for (int nt = 0; nt < 4; nt++) {
        u16x4 pk = { f2bf(acc[mt][nt][0]), f2bf(acc[mt][nt][1]),
                     f2bf(acc[mt][nt][2]), f2bf(acc[mt][nt][3]) };
        *(u16x4*)&ep[(nt * 16 + col) * 72 + mt * 16 + quad * 4] = pk;
      }
  } else {
#pragma unroll
    for (int mt = 0; mt < 4; mt++)
#pragma unroll
      for (int nt = 0; nt < 4; nt++)
#pragma unroll
        for (int r = 0; r < 4; r++)
          ep[(mt * 16 + quad * 4 + r) * 72 + nt * 16 + col] = f2bf(acc[mt][nt][r]);
  }

  const int bb = m0 >> 11;
  const int h  = (n0 >> 6) + wn;
  const int bh = bb * 16 + h;

  if (z == 0) {
    const int qbase = (m0 & 2047) + wm * 64;
    u16* dst = QH + ((size_t)bh * SEQ + qbase) * 64;
#pragma unroll
    for (int i = 0; i < 8; i++) {
      const int f  = i * 1024 + lane * 16;
      const int ml = i * 8 + (lane >> 3), nl = (lane & 7) * 8;
      *(bf8*)(dst + (f >> 1)) = *(const bf8*)&ep[ml * 72 + nl];
    }
  } else if (z == 1) {
    const int kt = (((m0 & 2047) >> 6) + wm);
    u16* dst = KH + (((size_t)bh * 32 + kt) << 12);
#pragma unroll
    for (int i = 0; i < 8; i++) {
      const int f   = i * 1024 + lane * 16;
      const int dh  = f >> 12;
      const int klc = (f >> 6) & 63;
      const int dlo = (lane & 3) * 8;
      const int fs  = f ^ (((klc >> 1) & 3) << 4);   // bank swizzle (within 64B row)
      *(bf8*)(dst + (fs >> 1)) = *(const bf8*)&ep[klc * 72 + dh * 32 + dlo];
    }
  } else {
    const int kt = (((m0 & 2047) >> 6) + wm);
    u16* dst = VTB + (((size_t)bh * 32 + kt) << 12);
#pragma unroll
    for (int i = 0; i < 8; i++) {
      const int f   = i * 1024 + lane * 16;
      const int kk  = f >> 12;
      const int d   = (f >> 6) & 63;
      const int klo = (lane & 3) * 8;
      const int fs  = f ^ (((d >> 1) & 3) << 4);     // bank swizzle (within 64B row)
      *(bf8*)(dst + (fs >> 1)) = *(const bf8*)&ep[d * 72 + kk * 32 + klo];
    }
  }
}

// ---------------- masked V mean (dead-row fallback). One wave per (b, e=h*64+d).
__global__ __launch_bounds__(256) void sumv(const u16* __restrict__ VTB,
                                            const float* __restrict__ vmask,
                                            float* __restrict__ fb)
{
  const int w = threadIdx.x >> 6, lane = threadIdx.x & 63;
  const int gw = blockIdx.x * 4 + w;
  const int b = gw >> 10, e = gw & 1023;
  const int h = e >> 6, d = e & 63;
  const int bh = b * 16 + h;
  const float* vm = vmask + b * SEQ;
  const int ksw = (lane & 31) ^ (((d >> 1) & 3) << 3);   // undo VTB swizzle
  float s = 0.f, c = 0.f;
  for (int kt = 0; kt < 32; kt++) {
    const u16 val = VTB[(((size_t)bh * 32 + kt) << 12) + (lane >> 5) * 2048 + d * 32 + ksw];
    const float m = vm[kt * 64 + lane];
    s += m * bf2f(val); c += m;
  }
#pragma unroll
  for (int o = 1; o < 64; o <<= 1) { s += __shfl_xor(s, o); c += __shfl_xor(c, o); }
  if (lane == 0) fb[gw] = s / c;
}

// ---------------- Flash attention, TRANSPOSED form: S^T = K Q^T, O^T = V^T P^T.
// One block per (b,h,qx): grid 1024 (3 resident blocks/CU).
// 2-deep counted-vmcnt K/V pipeline: stage tile it+2 after the release barrier,
// wait vmcnt(4) at the top (vmcnt(0) only on the final tile). Heavy-first qx
// ordering; XCD-clustered (b,h); swizzled K/V frag reads; setprio on MFMA.
__global__ __launch_bounds__(256) void attn(
    const u16* __restrict__ QH, const u16* __restrict__ KH, const u16* __restrict__ VTB,
    const float* __restrict__ vmask, const float* __restrict__ qmask,
    const float* __restrict__ fb, float* __restrict__ OUT)
{
  __shared__ float pen[SEQ];            // (1-vm)*1e10*log2e
  __shared__ u16   sK[2][4096];         // [dh2][64key][32d] x2 (swizzled)
  __shared__ u16   sV[2][4096];         // [kk2][64d][32k]   x2 (swizzled)
  __shared__ u16   P[4 * 16 * 72];      // per-wave P^T as [q16][keypad72]

  const int tid = threadIdx.x, lane = tid & 63, w = tid >> 6;
  const int i   = blockIdx.x;           // 0..1023
  const int xcd = i & 7;
  const int j   = i >> 3;               // 0..127
  const int qx  = j >> 2;               // heavy blocks (small qx) dispatch first
  const int bh  = xcd + 8 * (j & 3);    // 4 (b,h) per XCD for K/V L2 locality
  const int b = bh >> 4, h = bh & 15;
  const int col = lane & 15, quad = lane >> 4;
  const int sq8 = (quad ^ ((col >> 1) & 3)) * 8;   // swizzled k-slot for A-frag reads
  const int wb = w * 16 * 72;

  for (int t = tid; t < SEQ; t += 256)
    pen[t] = (1.0f - vmask[b * SEQ + t]) * BIG2F;

  const u16* kbase = KH  + (((size_t)bh * 32) << 12);
  const u16* vbase = VTB + (((size_t)bh * 32) << 12);

  const int q0 = qx * 64;

  // Q as B-frag: n = q = w*16+col, k = d
  bf8 bQ[2];
#pragma unroll
  for (int dh = 0; dh < 2; dh++)
    bQ[dh] = *(const bf8*)&QH[((size_t)bh * SEQ + q0 + w * 16 + col) * 64 + dh * 32 + quad * 8];

  const f4 zero = {0.f, 0.f, 0.f, 0.f};
  f4 accO[4];                           // O^T: [d-tile nt][r]: d = nt*16+quad*4+r, q = w*16+col
  float l_acc = 0.f;                    // softmax denom for q = w*16+col
#pragma unroll
  for (int t = 0; t < 4; t++) accO[t] = zero;

#define ASTAGE(BUF, KT) do { \
    const size_t toff_ = ((size_t)(KT) << 12) + w * 1024 + lane * 8; \
    gl_lds16(kbase + toff_,       &sK[(BUF)][w * 1024]); \
    gl_lds16(kbase + toff_ + 512, &sK[(BUF)][w * 1024 + 512]); \
    gl_lds16(vbase + toff_,       &sV[(BUF)][w * 1024]); \
    gl_lds16(vbase + toff_ + 512, &sV[(BUF)][w * 1024 + 512]); \
  } while (0)

  const int ntile = 32 - qx;
  // prologue: 2 tiles in flight (8 vmem ops/wave). Tile qx+1 may overshoot to
  // kt=32 when ntile==1: staged into LDS but never read; the global read stays
  // inside the workspace (KH is followed by VTB, VTB by fb) -- harmless.
  ASTAGE(0, qx);
  ASTAGE(1, qx + 1);

  for (int it = 0; it < ntile; it++) {
    // top: current tile's 4 loads done (next tile's stay in flight), own LDS
    // writes (pen at it=0, P/ds activity otherwise) drained for barrier safety.
    if (it + 1 < ntile) asm volatile("s_waitcnt vmcnt(4) lgkmcnt(0)" ::: "memory");
    else                asm volatile("s_waitcnt vmcnt(0) lgkmcnt(0)" ::: "memory");
    __builtin_amdgcn_s_barrier();
    __builtin_amdgcn_sched_barrier(0);

    const u16* cK = sK[it & 1];
    const u16* cV = sV[it & 1];
    const int k0 = (qx + it) * 64;

    // pen loads hoisted ahead of the MFMA cluster (independent of accS)
    fv4 pv[4];
#pragma unroll
    for (int nt = 0; nt < 4; nt++) pv[nt] = *(const fv4*)&pen[k0 + nt * 16 + quad * 4];

    // S^T = K Q^T : A = K (m=key), B = Q (n=q)
    f4 accS[4];
#pragma unroll
    for (int t = 0; t < 4; t++) accS[t] = zero;
    __builtin_amdgcn_s_setprio(1);
#pragma unroll
    for (int nt = 0; nt < 4; nt++)
#pragma unroll
      for (int dh = 0; dh < 2; dh++) {
        bf8 aK = *(const bf8*)&cK[dh * 2048 + (nt * 16 + col) * 32 + sq8];
        accS[nt] = __builtin_amdgcn_mfma_f32_16x16x32_bf16(aK, bQ[dh], accS[nt], 0, 0, 0);
      }
    __builtin_amdgcn_s_setprio(0);

    // p = exp2(s*C2 - pen2 [- causal]) ; accS[nt][r] = S[key=k0+nt*16+quad*4+r][q]
    float p[4][4];
    if (it == 0) {                      // diagonal tile: key_local <= q_local penalized
#pragma unroll
      for (int nt = 0; nt < 4; nt++)
#pragma unroll
        for (int r = 0; r < 4; r++) {
          float sv = fmaf(accS[nt][r], C2, -pv[nt][r]);
          if (nt * 16 + quad * 4 + r <= w * 16 + col) sv -= BIG2F;
          p[nt][r] = exp2_hw(sv);
        }
    } else {
#pragma unroll
      for (int nt = 0; nt < 4; nt++)
#pragma unroll
        for (int r = 0; r < 4; r++)
          p[nt][r] = exp2_hw(fmaf(accS[nt][r], C2, -pv[nt][r]));
    }
#pragma unroll
    for (int nt = 0; nt < 4; nt++)
      l_acc += (p[nt][0] + p[nt][1]) + (p[nt][2] + p[nt][3]);

    // P^T -> wave-private LDS [q=col][4 consecutive keys] : one b64 per nt
#pragma unroll
    for (int nt = 0; nt < 4; nt++) {
      union { u16x4 v; u16 u[4]; } pk;
      union { __hip_bfloat162 h2; u16 u[2]; } c0, c1;
      float2 f01; f01.x = p[nt][0]; f01.y = p[nt][1];
      float2 f23; f23.x = p[nt][2]; f23.y = p[nt][3];
      c0.h2 = __float22bfloat162_rn(f01);
      c1.h2 = __float22bfloat162_rn(f23);
      pk.u[0] = c0.u[0]; pk.u[1] = c0.u[1]; pk.u[2] = c1.u[0]; pk.u[3] = c1.u[1];
      *(u16x4*)&P[wb + col * 72 + nt * 16 + quad * 4] = pk.v;
    }

    // O^T += V^T P^T : A = V^T (m=d), B = P^T (n=q, k=key)
    __builtin_amdgcn_s_setprio(1);
#pragma unroll
    for (int kk = 0; kk < 2; kk++) {
      bf8 bP = *(const bf8*)&P[wb + col * 72 + kk * 32 + quad * 8];
#pragma unroll
      for (int nt = 0; nt < 4; nt++) {
        bf8 aV = *(const bf8*)&cV[kk * 2048 + (nt * 16 + col) * 32 + sq8];
        accO[nt] = __builtin_amdgcn_mfma_f32_16x16x32_bf16(aV, bP, accO[nt], 0, 0, 0);
      }
    }
    __builtin_amdgcn_s_setprio(0);

    // release: all waves done reading buf[it&1], then restage it 2 ahead
    asm volatile("s_waitcnt lgkmcnt(0)" ::: "memory");
    __builtin_amdgcn_sched_barrier(0);
    __builtin_amdgcn_s_barrier();
    if (it + 2 < ntile) { ASTAGE((it & 1), qx + it + 2); }
  }
#undef ASTAGE

  // epilogue: reduce l over quads (lane bits 4-5), divide, q_mask, dwordx4 stores
  float l = l_acc;
  l += __shfl_xor(l, 16); l += __shfl_xor(l, 32);
  const int q = q0 + w * 16 + col;
  const float qm = qmask[b * SEQ + q];
  float* op = OUT + (size_t)(b * SEQ + q) * EMB + h * 64;
  if (l == 0.0f) {                      // dead row: uniform masked-average fallback
#pragma unroll
    for (int nt = 0; nt < 4; nt++) {
      fv4 f = *(const fv4*)&fb[b * 1024 + h * 64 + nt * 16 + quad * 4];
      f *= qm;
      *(fv4*)(op + nt * 16 + quad * 4) = f;
    }
  } else {
    const float s = qm / l;
#pragma unroll
    for (int nt = 0; nt < 4; nt++) {
      fv4 f = { accO[nt][0] * s, accO[nt][1] * s, accO[nt][2] * s, accO[nt][3] * s };
      *(fv4*)(op + nt * 16 + quad * 4) = f;
    }
  }
}

extern "C" void kernel_launch(void* const* d_in, const int* in_sizes, int n_in,
                              void* d_out, int out_size, void* d_ws, size_t ws_size,
                              hipStream_t stream)
{
  const float* q  = (const float*)d_in[0];
  const float* k  = (const float*)d_in[1];
  const float* v  = (const float*)d_in[2];
  const float* vm = (const float*)d_in[3];
  const float* qm = (const float*)d_in[4];
  const float* Wq = (const float*)d_in[5];
  const float* Wk = (const float*)d_in[6];
  const float* Wv = (const float*)d_in[7];
  float* out = (float*)d_out;

  const size_t NBIG = (size_t)B_ * SEQ * EMB;   // 4 Mi
  const size_t NW   = (size_t)EMB * EMB;        // 1 Mi

  u16* qb  = (u16*)d_ws;
  u16* kb  = qb  + NBIG;
  u16* vb  = kb  + NBIG;
  u16* Wqb = vb  + NBIG;
  u16* Wkb = Wqb + NW;
  u16* Wvb = Wkb + NW;
  u16* QH  = Wvb + NW;
  u16* KH  = QH  + NBIG;
  u16* VTB = KH  + NBIG;
  float* fb = (float*)(VTB + NBIG);             // [2][1024] f32

  CvtArgs ca;
  ca.src[0] = q;  ca.dst[0] = qb;  ca.n[0] = (int)NBIG;
  ca.src[1] = k;  ca.dst[1] = kb;  ca.n[1] = (int)NBIG;
  ca.src[2] = v;  ca.dst[2] = vb;  ca.n[2] = (int)NBIG;
  ca.src[3] = Wq; ca.dst[3] = Wqb; ca.n[3] = (int)NW;
  ca.src[4] = Wk; ca.dst[4] = Wkb; ca.n[4] = (int)NW;
  ca.src[5] = Wv; ca.dst[5] = Wvb; ca.n[5] = (int)NW;

  cvt_bf16<<<dim3((unsigned)(NBIG / 8 / 256), 6, 1), 256, 0, stream>>>(ca);
  proj_gemm<<<dim3(32, 8, 3), 256, 0, stream>>>(qb, kb, vb, Wqb, Wkb, Wvb, QH, KH, VTB);
  sumv<<<dim3(512, 1, 1), 256, 0, stream>>>(VTB, vm, fb);
  attn<<<dim3(1024, 1, 1), 256, 0, stream>>>(QH, KH, VTB, vm, qm, fb, out);
}